// Round 1
// baseline (260.509 us; speedup 1.0000x reference)
//
#include <hip/hip_runtime.h>
#include <hip/hip_bf16.h>
#include <stdint.h>
#include <stddef.h>

#define T_SEQ 2048
#define DMODEL 2048
#define NHEADS 32
#define NKV 8
#define HD 64
#define NQD (NHEADS * HD)        // 2048
#define NKVD (NKV * HD)          // 512
#define QKVN (NQD + 2 * NKVD)    // 3072

typedef __bf16 bf16_t;
typedef __bf16 bf16x8 __attribute__((ext_vector_type(8)));
typedef __bf16 bf16x2 __attribute__((ext_vector_type(2)));
typedef float f32x4 __attribute__((ext_vector_type(4)));

typedef __attribute__((address_space(1))) void gvoid_t;
typedef __attribute__((address_space(3))) void lvoid_t;

__device__ __forceinline__ void gload_lds16(const void* g, void* l) {
  __builtin_amdgcn_global_load_lds((gvoid_t*)g, (lvoid_t*)l, 16, 0, 0);
}

// ---------------- elementwise cast f32 -> bf16 (8 elems/thread) ----------------
__global__ __launch_bounds__(256) void cast_f32_bf16_kernel(
    const float* __restrict__ in, bf16_t* __restrict__ out, int n8) {
  int i = blockIdx.x * 256 + threadIdx.x;
  if (i >= n8) return;
  const float4* p = (const float4*)in + (size_t)i * 2;
  float4 a = p[0], b = p[1];
  bf16x8 o = {(bf16_t)a.x, (bf16_t)a.y, (bf16_t)a.z, (bf16_t)a.w,
              (bf16_t)b.x, (bf16_t)b.y, (bf16_t)b.z, (bf16_t)b.w};
  *(bf16x8*)(out + (size_t)i * 8) = o;
}

// ---------------- tiled transpose + cast: out[c][r] = (bf16) in[r][c] ----------------
__global__ __launch_bounds__(256) void transpose_cast_kernel(
    const float* __restrict__ in, bf16_t* __restrict__ out,
    int R, int C, int ldin, int ldout) {
  __shared__ float tile[32][33];
  const int c0 = blockIdx.x * 32, r0 = blockIdx.y * 32;
  const int tx = threadIdx.x & 31, ty = threadIdx.x >> 5;
#pragma unroll
  for (int i = 0; i < 32; i += 8)
    tile[ty + i][tx] = in[(size_t)(r0 + ty + i) * ldin + c0 + tx];
  __syncthreads();
#pragma unroll
  for (int i = 0; i < 32; i += 8)
    out[(size_t)(c0 + ty + i) * ldout + r0 + tx] = (bf16_t)tile[tx][ty + i];
}

// ---------------- RoPE + cast: src is fp32 [T][ldin] (already col-offset), dst bf16 [T][H*64] ----------------
__global__ __launch_bounds__(256) void rope_cast_kernel(
    const float* __restrict__ src, const float* __restrict__ fc,
    bf16_t* __restrict__ dst, int H, int ldin) {
  const int i = blockIdx.x * 256 + threadIdx.x;  // global pair index
  const int npr = H * 32;
  const int t = i / npr;
  const int rem = i - t * npr;
  const int h = rem >> 5, fi = rem & 31;
  const float2 rein = *(const float2*)&src[(size_t)t * ldin + h * 64 + fi * 2];
  const float2 cs = *(const float2*)&fc[((size_t)t * 32 + fi) * 2];
  const float o0 = rein.x * cs.x - rein.y * cs.y;
  const float o1 = rein.x * cs.y + rein.y * cs.x;
  bf16x2 ob = {(bf16_t)o0, (bf16_t)o1};
  *(bf16x2*)&dst[(size_t)t * (H * 64) + h * 64 + fi * 2] = ob;
}

// ---------------- GEMM: C(f32, MxN) = A(bf16, MxK) * BT(bf16, NxK)^T ----------------
// 128x128 tile, BK=32, 256 threads (4 waves, 2x2), global_load_lds staging.
__global__ __launch_bounds__(256) void gemm_bt_kernel(
    const bf16_t* __restrict__ A, const bf16_t* __restrict__ BT,
    float* __restrict__ C, int M, int N, int K) {
  __shared__ bf16_t As[128 * 32];
  __shared__ bf16_t Bs[128 * 32];
  const int tid = threadIdx.x;
  const int lane = tid & 63;
  const int w = tid >> 6;
  const int lr = lane & 15, lg = lane >> 4;
  const int m0 = blockIdx.y * 128, n0 = blockIdx.x * 128;
  const int wm = (w >> 1) * 64, wn = (w & 1) * 64;

  const int c1 = tid, c2 = tid + 256;
  const bf16_t* gA1 = A + (size_t)(m0 + (c1 >> 2)) * K + (c1 & 3) * 8;
  const bf16_t* gA2 = A + (size_t)(m0 + (c2 >> 2)) * K + (c2 & 3) * 8;
  const bf16_t* gB1 = BT + (size_t)(n0 + (c1 >> 2)) * K + (c1 & 3) * 8;
  const bf16_t* gB2 = BT + (size_t)(n0 + (c2 >> 2)) * K + (c2 & 3) * 8;
  bf16_t* lA1 = As + c1 * 8;
  bf16_t* lA2 = As + c2 * 8;
  bf16_t* lB1 = Bs + c1 * 8;
  bf16_t* lB2 = Bs + c2 * 8;

  f32x4 acc[4][4] = {};

  for (int k0 = 0; k0 < K; k0 += 32) {
    gload_lds16(gA1 + k0, lA1);
    gload_lds16(gA2 + k0, lA2);
    gload_lds16(gB1 + k0, lB1);
    gload_lds16(gB2 + k0, lB2);
    __syncthreads();
    bf16x8 af[4], bfr[4];
#pragma unroll
    for (int mi = 0; mi < 4; ++mi)
      af[mi] = *(const bf16x8*)&As[(wm + mi * 16 + lr) * 32 + lg * 8];
#pragma unroll
    for (int nj = 0; nj < 4; ++nj)
      bfr[nj] = *(const bf16x8*)&Bs[(wn + nj * 16 + lr) * 32 + lg * 8];
#pragma unroll
    for (int mi = 0; mi < 4; ++mi)
#pragma unroll
      for (int nj = 0; nj < 4; ++nj)
        acc[mi][nj] = __builtin_amdgcn_mfma_f32_16x16x32_bf16(
            af[mi], bfr[nj], acc[mi][nj], 0, 0, 0);
    __syncthreads();
  }

#pragma unroll
  for (int mi = 0; mi < 4; ++mi)
#pragma unroll
    for (int nj = 0; nj < 4; ++nj) {
      const int row = m0 + wm + mi * 16 + lg * 4;
      const int col = n0 + wn + nj * 16 + lr;
#pragma unroll
      for (int r = 0; r < 4; ++r)
        C[(size_t)(row + r) * N + col] = acc[mi][nj][r];
    }
}

// ---------------- causal GQA flash attention ----------------
// grid = (T/128, NHEADS); block = 256 (4 waves, each owns 32 q-rows).
// Q: bf16 [T][2048], Kb: bf16 [T][512], VT: bf16 [512][T], Y: bf16 [T][2048]
__global__ __launch_bounds__(256) void attn_kernel(
    const bf16_t* __restrict__ Q, const bf16_t* __restrict__ Kb,
    const bf16_t* __restrict__ VT, bf16_t* __restrict__ Y) {
  __shared__ char plds_all[4][32 * 128];  // per-wave P tile [32][64] bf16, XOR-swizzled
  const int qt = blockIdx.x, h = blockIdx.y;
  const int kh = h >> 2;
  const int tid = threadIdx.x, lane = tid & 63, w = tid >> 6;
  const int lr = lane & 15, lg = lane >> 4;
  const int q0 = qt * 128 + w * 32;
  char* pb = plds_all[w];

  // Q fragments hoisted into registers
  bf16x8 qf[2][2];
#pragma unroll
  for (int i = 0; i < 2; ++i)
#pragma unroll
    for (int ks = 0; ks < 2; ++ks)
      qf[i][ks] = *(const bf16x8*)&Q[(size_t)(q0 + i * 16 + lr) * NQD + h * HD + ks * 32 + lg * 8];

  float m_i[8], l_i[8];
  f32x4 acc_o[2][4] = {};
#pragma unroll
  for (int z = 0; z < 8; ++z) { m_i[z] = -1e30f; l_i[z] = 0.f; }

  const int wend = q0 + 32;  // per-wave causal bound
  for (int s0 = 0; s0 < wend; s0 += 64) {
    // K fragments (B-operand of QK^T) straight from global (L2-resident)
    bf16x8 kf[4][2];
#pragma unroll
    for (int j = 0; j < 4; ++j)
#pragma unroll
      for (int ks = 0; ks < 2; ++ks)
        kf[j][ks] = *(const bf16x8*)&Kb[(size_t)(s0 + j * 16 + lr) * NKVD + kh * HD + ks * 32 + lg * 8];

    f32x4 sacc[2][4] = {};
#pragma unroll
    for (int i = 0; i < 2; ++i)
#pragma unroll
      for (int j = 0; j < 4; ++j)
#pragma unroll
        for (int ks = 0; ks < 2; ++ks)
          sacc[i][j] = __builtin_amdgcn_mfma_f32_16x16x32_bf16(
              qf[i][ks], kf[j][ks], sacc[i][j], 0, 0, 0);

    // online softmax, 8 rows per lane-state (i, r); 16 lanes share a row
#pragma unroll
    for (int i = 0; i < 2; ++i)
#pragma unroll
      for (int r = 0; r < 4; ++r) {
        const int idx = i * 4 + r;
        const int t = q0 + i * 16 + lg * 4 + r;
        const int row = i * 16 + lg * 4 + r;
        float sv[4];
        float pm = -1e30f;
#pragma unroll
        for (int j = 0; j < 4; ++j) {
          float v = sacc[i][j][r] * 0.125f;
          if (s0 + j * 16 + lr > t) v = -1e30f;
          sv[j] = v;
          pm = fmaxf(pm, v);
        }
#pragma unroll
        for (int off = 1; off < 16; off <<= 1)
          pm = fmaxf(pm, __shfl_xor(pm, off));
        const float mnew = fmaxf(m_i[idx], pm);
        const float escale = __expf(m_i[idx] - mnew);
        m_i[idx] = mnew;
        float rs = 0.f;
#pragma unroll
        for (int j = 0; j < 4; ++j) {
          const float pv = __expf(sv[j] - mnew);
          rs += pv;
          const int cb = ((j * 16 + lr) * 2) ^ ((row & 7) << 4);
          *(bf16_t*)(pb + row * 128 + cb) = (bf16_t)pv;
        }
#pragma unroll
        for (int off = 1; off < 16; off <<= 1)
          rs += __shfl_xor(rs, off);
        l_i[idx] = l_i[idx] * escale + rs;
#pragma unroll
        for (int df = 0; df < 4; ++df)
          acc_o[i][df][r] *= escale;
      }

    // P (A-operand) back from swizzled LDS as bf16x8 fragments
    bf16x8 pa[2][2];
#pragma unroll
    for (int i = 0; i < 2; ++i)
#pragma unroll
      for (int ks = 0; ks < 2; ++ks) {
        const int row = i * 16 + lr;
        const int cb = (ks * 64 + lg * 16) ^ ((row & 7) << 4);
        pa[i][ks] = *(const bf16x8*)(pb + row * 128 + cb);
      }
    // V fragments (B-operand of PV) from transposed V
    bf16x8 vf[2][4];
#pragma unroll
    for (int ks = 0; ks < 2; ++ks)
#pragma unroll
      for (int df = 0; df < 4; ++df)
        vf[ks][df] = *(const bf16x8*)&VT[(size_t)(kh * HD + df * 16 + lr) * T_SEQ + s0 + ks * 32 + lg * 8];
#pragma unroll
    for (int i = 0; i < 2; ++i)
#pragma unroll
      for (int df = 0; df < 4; ++df)
#pragma unroll
        for (int ks = 0; ks < 2; ++ks)
          acc_o[i][df] = __builtin_amdgcn_mfma_f32_16x16x32_bf16(
              pa[i][ks], vf[ks][df], acc_o[i][df], 0, 0, 0);
  }

  // normalize + write y (bf16)
#pragma unroll
  for (int i = 0; i < 2; ++i)
#pragma unroll
    for (int r = 0; r < 4; ++r) {
      const float inv = 1.f / l_i[i * 4 + r];
      const int t = q0 + i * 16 + lg * 4 + r;
#pragma unroll
      for (int df = 0; df < 4; ++df)
        Y[(size_t)t * NQD + h * HD + df * 16 + lr] = (bf16_t)(acc_o[i][df][r] * inv);
    }
}

extern "C" void kernel_launch(void* const* d_in, const int* in_sizes, int n_in,
                              void* d_out, int out_size, void* d_ws, size_t ws_size,
                              hipStream_t stream) {
  const float* x = (const float*)d_in[0];
  const float* fc = (const float*)d_in[1];
  const float* wq = (const float*)d_in[2];
  const float* wk = (const float*)d_in[3];
  const float* wv = (const float*)d_in[4];
  const float* wo = (const float*)d_in[5];
  float* out = (float*)d_out;
  char* ws = (char*)d_ws;

  // workspace arena (36 MB), aliased by lifetime:
  bf16_t* xb   = (bf16_t*)(ws + 0);                 // [2048][2048]  8 MB   (dead after QKV gemm)
  bf16_t* wT   = (bf16_t*)(ws + (8u << 20));        // [3072][2048] 12 MB   (dead after QKV gemm)
  float*  qkvf = (float*)(ws + (20u << 20));        // [2048][3072] 24 MB fp32 (dead after rope/vT)
  bf16_t* qb   = (bf16_t*)(ws + (8u << 20));        // [2048][2048]  8 MB (over wT)
  bf16_t* kb   = (bf16_t*)(ws + (16u << 20));       // [2048][512]   2 MB (over wT)
  bf16_t* vt   = (bf16_t*)(ws + (18u << 20));       // [512][2048]   2 MB (over wT)
  bf16_t* woT  = (bf16_t*)(ws + (20u << 20));       // [2048][2048]  8 MB (over qkvf)
  bf16_t* yb   = (bf16_t*)(ws + (28u << 20));       // [2048][2048]  8 MB (over qkvf)

  // 1. x -> bf16
  hipLaunchKernelGGL(cast_f32_bf16_kernel, dim3(2048), dim3(256), 0, stream,
                     x, xb, (T_SEQ * DMODEL) / 8);
  // 2. weight transposes into fused [3072][2048] B^T panel
  hipLaunchKernelGGL(transpose_cast_kernel, dim3(64, 64), dim3(256), 0, stream,
                     wq, wT, DMODEL, NQD, NQD, DMODEL);
  hipLaunchKernelGGL(transpose_cast_kernel, dim3(16, 64), dim3(256), 0, stream,
                     wk, wT + (size_t)NQD * DMODEL, DMODEL, NKVD, NKVD, DMODEL);
  hipLaunchKernelGGL(transpose_cast_kernel, dim3(16, 64), dim3(256), 0, stream,
                     wv, wT + (size_t)(NQD + NKVD) * DMODEL, DMODEL, NKVD, NKVD, DMODEL);
  // 3. fused QKV projection: qkvf = x @ [wq|wk|wv]
  hipLaunchKernelGGL(gemm_bt_kernel, dim3(QKVN / 128, T_SEQ / 128), dim3(256), 0, stream,
                     xb, wT, qkvf, T_SEQ, QKVN, DMODEL);
  // 4. RoPE + cast Q, K
  hipLaunchKernelGGL(rope_cast_kernel, dim3((T_SEQ * NHEADS * 32) / 256), dim3(256), 0, stream,
                     qkvf, fc, qb, NHEADS, QKVN);
  hipLaunchKernelGGL(rope_cast_kernel, dim3((T_SEQ * NKV * 32) / 256), dim3(256), 0, stream,
                     qkvf + NQD, fc, kb, NKV, QKVN);
  // 5. V -> VT (bf16, [512][2048])
  hipLaunchKernelGGL(transpose_cast_kernel, dim3(16, 64), dim3(256), 0, stream,
                     qkvf + NQD + NKVD, vt, T_SEQ, NKVD, QKVN, T_SEQ);
  // 6. wo -> woT
  hipLaunchKernelGGL(transpose_cast_kernel, dim3(64, 64), dim3(256), 0, stream,
                     wo, woT, NQD, DMODEL, DMODEL, NQD);
  // 7. attention
  hipLaunchKernelGGL(attn_kernel, dim3(T_SEQ / 128, NHEADS), dim3(256), 0, stream,
                     qb, kb, vt, yb);
  // 8. output projection -> d_out (fp32)
  hipLaunchKernelGGL(gemm_bt_kernel, dim3(DMODEL / 128, T_SEQ / 128), dim3(256), 0, stream,
                     yb, woT, out, T_SEQ, DMODEL, NQD);
}